// Round 3
// baseline (541.103 us; speedup 1.0000x reference)
//
#include <hip/hip_runtime.h>

#define F_DIM   128
#define D_DIM   128
#define BATCH_N 8192
#define LN_EPS  1e-5f
#define ROWS_PER_BLOCK 64   // 8 iterations of 8 rows; 32 KB of fp32 stores per block

// LayerNorm of an affine function of scalar x collapses to closed form:
//   emb - mean = x*Wc + bc          (Wc = W[f]-mean_d W[f], bc = b[f]-mean_d b[f])
//   var        = A x^2 + 2B x + C   (A=mean Wc^2, B=mean Wc*bc, C=mean bc^2)
//   out[d]     = (x*rsq)*Wc[d]*g[d] + rsq*bc[d]*g[d] + beta[d],  rsq=rsqrt(var+eps)
// Each block recomputes the per-f constants in LDS, then streams 64 rows of
// coalesced float4 stores. All I/O is fp32 per the reference dtypes.
__global__ __launch_bounds__(256) void fused_emb_ln_kernel(const float* __restrict__ x,
                                                           const float* __restrict__ W,
                                                           const float* __restrict__ b,
                                                           const float* __restrict__ gamma,
                                                           const float* __restrict__ beta,
                                                           float* __restrict__ out) {
    const int tid   = threadIdx.x;
    const int f     = blockIdx.x >> 7;                    // 128 blocks per feature
    const int nbase = (blockIdx.x & 127) * ROWS_PER_BLOCK;

    __shared__ float r1[128], r2[128], r3[128];
    __shared__ float sWg[128], sBg[128], sBe[128];

    float w = 0.f, bb = 0.f, g = 0.f, be = 0.f;
    if (tid < 128) {
        w  = W[f * D_DIM + tid];
        bb = b[f * D_DIM + tid];
        g  = gamma[tid];
        be = beta[tid];
        r1[tid] = w; r2[tid] = bb;
    }
    __syncthreads();
    for (int off = 64; off > 0; off >>= 1) {
        if (tid < off) { r1[tid] += r1[tid + off]; r2[tid] += r2[tid + off]; }
        __syncthreads();
    }
    const float inv = 1.0f / 128.0f;
    const float mw  = r1[0] * inv;
    const float mbm = r2[0] * inv;
    __syncthreads();                                      // all reads of r1[0]/r2[0] done before rewrite
    if (tid < 128) {
        const float wc = w - mw;
        const float bc = bb - mbm;
        r1[tid] = wc * wc; r2[tid] = wc * bc; r3[tid] = bc * bc;
        sWg[tid] = wc * g; sBg[tid] = bc * g; sBe[tid] = be;
    }
    __syncthreads();
    for (int off = 64; off > 0; off >>= 1) {
        if (tid < off) { r1[tid] += r1[tid + off]; r2[tid] += r2[tid + off]; r3[tid] += r3[tid + off]; }
        __syncthreads();
    }
    const float A  = r1[0] * inv;
    const float B2 = 2.0f * r2[0] * inv;
    const float Cp = r3[0] * inv + LN_EPS;

    const int dv = tid & 31;                              // float4 index within the d-row (0..31)
    const int r0 = tid >> 5;                              // 0..7 rows per iteration
    const float4* Wg4 = (const float4*)sWg;
    const float4* Bg4 = (const float4*)sBg;
    const float4* Be4 = (const float4*)sBe;
    const float4 w0 = Wg4[dv];
    const float4 b0 = Bg4[dv];
    const float4 e0 = Be4[dv];

    float4* out4 = (float4*)out;
    #pragma unroll
    for (int it = 0; it < ROWS_PER_BLOCK / 8; ++it) {
        const int n  = nbase + it * 8 + r0;
        const float xf = x[n * F_DIM + f];

        float var = fmaf(xf, fmaf(xf, A, B2), Cp);
        var = fmaxf(var, 1e-7f);                          // guard fp32 rounding (true var >= eps)
        const float rsq = rsqrtf(var);
        const float xr  = xf * rsq;

        float4 o;
        o.x = fmaf(xr, w0.x, fmaf(rsq, b0.x, e0.x));
        o.y = fmaf(xr, w0.y, fmaf(rsq, b0.y, e0.y));
        o.z = fmaf(xr, w0.z, fmaf(rsq, b0.z, e0.z));
        o.w = fmaf(xr, w0.w, fmaf(rsq, b0.w, e0.w));

        out4[(f * BATCH_N + n) * 32 + dv] = o;            // wave = 1 KiB contiguous
    }
}

extern "C" void kernel_launch(void* const* d_in, const int* in_sizes, int n_in,
                              void* d_out, int out_size, void* d_ws, size_t ws_size,
                              hipStream_t stream) {
    const float* x     = (const float*)d_in[0];
    const float* W     = (const float*)d_in[1];
    const float* b     = (const float*)d_in[2];
    const float* gamma = (const float*)d_in[3];
    const float* beta  = (const float*)d_in[4];
    float* out = (float*)d_out;
    (void)d_ws; (void)ws_size;

    const int nblocks = F_DIM * (BATCH_N / ROWS_PER_BLOCK);   // 128 * 128 = 16384
    fused_emb_ln_kernel<<<dim3(nblocks), dim3(256), 0, stream>>>(x, W, b, gamma, beta, out);
}